// Round 11
// baseline (422.141 us; speedup 1.0000x reference)
//
#include <hip/hip_runtime.h>
#include <hip/hip_bf16.h>

// Problem constants (match reference)
#define NN 50000
#define NE 800000
#define NG 500
// D_IN = D_HID = 128, D_OUT = 64

// degree/placement decomposition
#define NR 8            // node ranges (LDS histogram = 2 x NN/NR ints = 50 KB)
#define NC 32           // edge chunks
#define RNG (NN / NR)   // 6250 nodes per range
#define CHE (NE / NC)   // 25000 edges per chunk
#define SCB 13          // scan blocks: ceil(NN / 4096)

// bf16 helpers (RNE pack, shift-unpack)
__device__ __forceinline__ unsigned f2bf(float f) {
    unsigned u = __float_as_uint(f);
    return (u + 0x7fffu + ((u >> 16) & 1u)) >> 16;
}
__device__ __forceinline__ float bf2f(unsigned u16) {
    return __uint_as_float(u16 << 16);
}

// ---------------------------------------------------------------------------
// 1) degree count with ZERO global atomics: LDS histograms + non-atomic flush.
__global__ __launch_bounds__(256) void degree_lds_kernel(
        const int* __restrict__ src, const int* __restrict__ dst,
        int* __restrict__ pin, int* __restrict__ pout) {
    __shared__ int hin[RNG], hout[RNG];
    const int tid   = threadIdx.x;
    const int r     = blockIdx.x & (NR - 1);
    const int c     = blockIdx.x / NR;
    const int rbase = r * RNG;
    for (int i = tid; i < RNG; i += 256) { hin[i] = 0; hout[i] = 0; }
    __syncthreads();
    const int4* s4 = (const int4*)(src + c * CHE);
    const int4* d4 = (const int4*)(dst + c * CHE);
    for (int i = tid; i < CHE / 4; i += 256) {
        int4 s = s4[i];
        int4 d = d4[i];
        unsigned a;
        a = (unsigned)(d.x - rbase); if (a < RNG) atomicAdd(&hin[a], 1);
        a = (unsigned)(d.y - rbase); if (a < RNG) atomicAdd(&hin[a], 1);
        a = (unsigned)(d.z - rbase); if (a < RNG) atomicAdd(&hin[a], 1);
        a = (unsigned)(d.w - rbase); if (a < RNG) atomicAdd(&hin[a], 1);
        a = (unsigned)(s.x - rbase); if (a < RNG) atomicAdd(&hout[a], 1);
        a = (unsigned)(s.y - rbase); if (a < RNG) atomicAdd(&hout[a], 1);
        a = (unsigned)(s.z - rbase); if (a < RNG) atomicAdd(&hout[a], 1);
        a = (unsigned)(s.w - rbase); if (a < RNG) atomicAdd(&hout[a], 1);
    }
    __syncthreads();
    for (int i = tid; i < RNG; i += 256) {
        pin [c * NN + rbase + i] = hin[i];
        pout[c * NN + rbase + i] = hout[i];
    }
}

// ---------------------------------------------------------------------------
// 2) reduce partials -> total in-degree + both norms (fused)
__global__ void reduce_norms_kernel(const int* __restrict__ pin, const int* __restrict__ pout,
                                    int* __restrict__ deg_in_tot,
                                    float* __restrict__ norm_in,
                                    float* __restrict__ norm_out, int n) {
    int i = blockIdx.x * blockDim.x + threadIdx.x;
    if (i >= n) return;
    int di = 0, dq = 0;
    #pragma unroll
    for (int c = 0; c < NC; c++) {
        di += pin [c * NN + i];
        dq += pout[c * NN + i];
    }
    deg_in_tot[i] = di;
    norm_in[i]  = di > 0 ? 1.0f / sqrtf((float)di) : 0.f;
    norm_out[i] = dq > 0 ? 1.0f / sqrtf((float)dq) : 0.f;
}

// ---------------------------------------------------------------------------
// 3a) per-4096-chunk sums (parallel, replaces the serial carry chain)
__global__ __launch_bounds__(1024) void scan_block_sums(
        const int* __restrict__ deg, int* __restrict__ bsum, int n) {
    __shared__ int wsum[16];
    const int tid = threadIdx.x, lane = tid & 63, wv = tid >> 6;
    const int i0 = blockIdx.x * 4096 + tid * 4;
    int s = 0;
    if (i0 + 3 < n) {
        int4 v = *(const int4*)(deg + i0);
        s = v.x + v.y + v.z + v.w;
    } else if (i0 < n) {
        s = deg[i0];
        if (i0 + 1 < n) s += deg[i0 + 1];
        if (i0 + 2 < n) s += deg[i0 + 2];
    }
    #pragma unroll
    for (int off = 32; off > 0; off >>= 1) s += __shfl_down(s, off);
    if (lane == 0) wsum[wv] = s;
    __syncthreads();
    if (wv == 0) {
        int t = (lane < 16) ? wsum[lane] : 0;
        #pragma unroll
        for (int off = 8; off > 0; off >>= 1) t += __shfl_down(t, off);
        if (lane == 0) bsum[blockIdx.x] = t;
    }
}

// 3b) per-chunk local scan + global base -> row_ptr; fused pcur computation.
__global__ __launch_bounds__(1024) void scan_apply(
        const int* __restrict__ deg, const int* __restrict__ bsum,
        const int* __restrict__ pin, int* __restrict__ row_ptr,
        int* __restrict__ pcur, int n) {
    __shared__ int wsum[16];
    const int tid = threadIdx.x, lane = tid & 63, wv = tid >> 6;
    const int b = blockIdx.x;
    int base = 0;
    for (int j = 0; j < SCB; j++) base += (j < b) ? bsum[j] : 0;
    const int i0 = b * 4096 + tid * 4;
    int v0 = 0, v1 = 0, v2 = 0, v3 = 0;
    if (i0 + 3 < n) {
        int4 v = *(const int4*)(deg + i0);
        v0 = v.x; v1 = v.y; v2 = v.z; v3 = v.w;
    } else if (i0 < n) {
        v0 = deg[i0];
        if (i0 + 1 < n) v1 = deg[i0 + 1];
        if (i0 + 2 < n) v2 = deg[i0 + 2];
    }
    const int l0 = v0, l1 = l0 + v1, l2 = l1 + v2, l3 = l2 + v3;
    int x = l3;
    #pragma unroll
    for (int off = 1; off < 64; off <<= 1) {
        int y = __shfl_up(x, off);
        if (lane >= off) x += y;
    }
    if (lane == 63) wsum[wv] = x;
    __syncthreads();
    if (wv == 0) {
        int t = (lane < 16) ? wsum[lane] : 0;
        int s = t;
        #pragma unroll
        for (int off = 1; off < 16; off <<= 1) {
            int y = __shfl_up(s, off);
            if (lane >= off) s += y;
        }
        if (lane < 16) wsum[lane] = s - t;   // exclusive wave offsets
    }
    __syncthreads();
    const int pre = base + wsum[wv] + (x - l3);  // global exclusive prefix at i0
    if (b == 0 && tid == 0) row_ptr[0] = 0;
    const int p0 = pre, p1 = pre + l0, p2 = pre + l1, p3 = pre + l2;
    if (i0 < n)     row_ptr[i0 + 1] = pre + l0;
    if (i0 + 1 < n) row_ptr[i0 + 2] = pre + l1;
    if (i0 + 2 < n) row_ptr[i0 + 3] = pre + l2;
    if (i0 + 3 < n) row_ptr[i0 + 4] = pre + l3;
    // fused chunk_offsets: pcur[c][i] = row_ptr[i] + prefix_c(pin[.][i])
    int off0 = p0, off1 = p1, off2 = p2, off3 = p3;
    #pragma unroll 4
    for (int c = 0; c < NC; c++) {
        if (i0 < n)     { pcur[c * NN + i0]     = off0; off0 += pin[c * NN + i0]; }
        if (i0 + 1 < n) { pcur[c * NN + i0 + 1] = off1; off1 += pin[c * NN + i0 + 1]; }
        if (i0 + 2 < n) { pcur[c * NN + i0 + 2] = off2; off2 += pin[c * NN + i0 + 2]; }
        if (i0 + 3 < n) { pcur[c * NN + i0 + 3] = off3; off3 += pin[c * NN + i0 + 3]; }
    }
}

// ---------------------------------------------------------------------------
// 4) CSR placement with ZERO global atomics: LDS cursors per (range,chunk).
__global__ __launch_bounds__(256) void place_lds_kernel(
        const int* __restrict__ src, const int* __restrict__ dst,
        const int* __restrict__ pcur, int* __restrict__ esrc) {
    __shared__ int lcur[RNG];
    const int tid   = threadIdx.x;
    const int r     = blockIdx.x & (NR - 1);
    const int c     = blockIdx.x / NR;
    const int rbase = r * RNG;
    for (int i = tid; i < RNG; i += 256) lcur[i] = pcur[c * NN + rbase + i];
    __syncthreads();
    const int4* s4 = (const int4*)(src + c * CHE);
    const int4* d4 = (const int4*)(dst + c * CHE);
    for (int i = tid; i < CHE / 4; i += 256) {
        int4 s = s4[i];
        int4 d = d4[i];
        unsigned a;
        a = (unsigned)(d.x - rbase); if (a < RNG) esrc[atomicAdd(&lcur[a], 1)] = s.x;
        a = (unsigned)(d.y - rbase); if (a < RNG) esrc[atomicAdd(&lcur[a], 1)] = s.y;
        a = (unsigned)(d.z - rbase); if (a < RNG) esrc[atomicAdd(&lcur[a], 1)] = s.z;
        a = (unsigned)(d.w - rbase); if (a < RNG) esrc[atomicAdd(&lcur[a], 1)] = s.w;
    }
}

// ---------------------------------------------------------------------------
// 5) GEMM: out = bf16((A*norm) @ W).  A is f32 (layer 1) or bf16 (layers 2,3).
template<int DO, int ROWS, bool A16>
__global__ __launch_bounds__(256) void gemm_reg_bf(
        const void* __restrict__ Av, const float* __restrict__ W,
        const float* __restrict__ norm, unsigned short* __restrict__ out, int nrows) {
    constexpr int DI  = 128;
    constexpr int KC  = 32;          // K-chunk
    constexpr int CXN = DO / 8;      // col-threads
    constexpr int RYN = 256 / CXN;   // row-threads; ROWS = RYN*8
    static_assert(ROWS == RYN * 8, "tile mismatch");
    __shared__ float At[KC][ROWS + 4];
    __shared__ float Wl[KC][DO + 4];

    const int tid  = threadIdx.x;
    const int cx   = tid % CXN;
    const int ry   = tid / CXN;
    const int row0 = blockIdx.x * ROWS;

    float acc[8][8] = {};

    for (int kc = 0; kc < DI; kc += KC) {
        __syncthreads();
        constexpr int AF4 = ROWS * KC / 4;
        #pragma unroll
        for (int i = tid; i < AF4; i += 256) {
            int r  = i >> 3;
            int kq = i & 7;
            int gr = row0 + r;
            float v0 = 0.f, v1 = 0.f, v2 = 0.f, v3 = 0.f;
            if (gr < nrows) {
                float s = norm[gr];
                if constexpr (A16) {
                    const unsigned short* A = (const unsigned short*)Av;
                    uint2 u = *(const uint2*)(A + (size_t)gr * DI + kc + kq * 4);
                    v0 = bf2f(u.x & 0xffffu) * s; v1 = bf2f(u.x >> 16) * s;
                    v2 = bf2f(u.y & 0xffffu) * s; v3 = bf2f(u.y >> 16) * s;
                } else {
                    const float* A = (const float*)Av;
                    float4 v = ((const float4*)(A + (size_t)gr * DI + kc))[kq];
                    v0 = v.x * s; v1 = v.y * s; v2 = v.z * s; v3 = v.w * s;
                }
            }
            At[kq * 4 + 0][r] = v0;
            At[kq * 4 + 1][r] = v1;
            At[kq * 4 + 2][r] = v2;
            At[kq * 4 + 3][r] = v3;
        }
        constexpr int WF4 = KC * DO / 4;
        #pragma unroll
        for (int i = tid; i < WF4; i += 256) {
            int k  = i / (DO / 4);
            int c4 = i % (DO / 4);
            *(float4*)&Wl[k][c4 * 4] = ((const float4*)(W + (size_t)(kc + k) * DO))[c4];
        }
        __syncthreads();
        #pragma unroll 4
        for (int k = 0; k < KC; k++) {
            float a[8], w[8];
            *(float4*)&a[0] = *(const float4*)&At[k][ry * 4];
            *(float4*)&a[4] = *(const float4*)&At[k][ROWS / 2 + ry * 4];
            *(float4*)&w[0] = *(const float4*)&Wl[k][cx * 4];
            *(float4*)&w[4] = *(const float4*)&Wl[k][DO / 2 + cx * 4];
            #pragma unroll
            for (int i = 0; i < 8; i++)
                #pragma unroll
                for (int j = 0; j < 8; j++)
                    acc[i][j] += a[i] * w[j];
        }
    }
    #pragma unroll
    for (int i = 0; i < 8; i++) {
        int r  = (i < 4) ? (ry * 4 + i) : (ROWS / 2 + ry * 4 + (i - 4));
        int gr = row0 + r;
        if (gr < nrows) {
            unsigned short* orow = out + (size_t)gr * DO;
            uint2 lo, hi;
            lo.x = f2bf(acc[i][0]) | (f2bf(acc[i][1]) << 16);
            lo.y = f2bf(acc[i][2]) | (f2bf(acc[i][3]) << 16);
            hi.x = f2bf(acc[i][4]) | (f2bf(acc[i][5]) << 16);
            hi.y = f2bf(acc[i][6]) | (f2bf(acc[i][7]) << 16);
            ((uint2*)orow)[cx]            = lo;   // cols cx*4..+3
            ((uint2*)(orow + DO / 2))[cx] = hi;   // cols DO/2+cx*4..+3
        }
    }
}

// ---------------------------------------------------------------------------
// 6a) 128-wide pull-aggregation, bf16 table in, **bf16 h out** (f32 accum).
__global__ __launch_bounds__(256) void aggregate128_h16(
        const unsigned short* __restrict__ t, const int* __restrict__ row_ptr,
        const int* __restrict__ esrc, const float* __restrict__ norm_in,
        const float* __restrict__ bias, unsigned short* __restrict__ out, int n) {
    const int wid  = (blockIdx.x * blockDim.x + threadIdx.x) >> 6;
    const int lane = threadIdx.x & 63;
    if (wid >= n) return;
    const int beg = row_ptr[wid], end = row_ptr[wid + 1];
    const unsigned* tp = (const unsigned*)t;   // 64 uints per row
    float ax0 = 0, ay0 = 0, ax1 = 0, ay1 = 0, ax2 = 0, ay2 = 0, ax3 = 0, ay3 = 0;
    int e = beg;
    for (; e + 3 < end; e += 4) {
        int s0 = esrc[e], s1 = esrc[e + 1], s2 = esrc[e + 2], s3 = esrc[e + 3];
        unsigned v0 = tp[(size_t)s0 * 64 + lane];
        unsigned v1 = tp[(size_t)s1 * 64 + lane];
        unsigned v2 = tp[(size_t)s2 * 64 + lane];
        unsigned v3 = tp[(size_t)s3 * 64 + lane];
        ax0 += bf2f(v0 & 0xffffu); ay0 += bf2f(v0 >> 16);
        ax1 += bf2f(v1 & 0xffffu); ay1 += bf2f(v1 >> 16);
        ax2 += bf2f(v2 & 0xffffu); ay2 += bf2f(v2 >> 16);
        ax3 += bf2f(v3 & 0xffffu); ay3 += bf2f(v3 >> 16);
    }
    for (; e < end; e++) {
        unsigned v = tp[(size_t)esrc[e] * 64 + lane];
        ax0 += bf2f(v & 0xffffu); ay0 += bf2f(v >> 16);
    }
    float ni = norm_in[wid];
    float2 bb = ((const float2*)bias)[lane];
    float ox = fmaxf((ax0 + ax1 + ax2 + ax3) * ni + bb.x, 0.f);
    float oy = fmaxf((ay0 + ay1 + ay2 + ay3) * ni + bb.y, 0.f);
    ((unsigned*)out)[(size_t)wid * 64 + lane] = f2bf(ox) | (f2bf(oy) << 16);
}

// 6b) 64-wide pull-aggregation, bf16 table in, f32 out (feeds readout).
__global__ __launch_bounds__(256) void aggregate64_f32(
        const unsigned short* __restrict__ t, const int* __restrict__ row_ptr,
        const int* __restrict__ esrc, const float* __restrict__ norm_in,
        const float* __restrict__ bias, float* __restrict__ out, int n) {
    const int wid  = (blockIdx.x * blockDim.x + threadIdx.x) >> 6;
    const int lane = threadIdx.x & 63;
    if (wid >= n) return;
    const int beg = row_ptr[wid], end = row_ptr[wid + 1];
    float a0 = 0, a1 = 0, a2 = 0, a3 = 0;
    int e = beg;
    for (; e + 3 < end; e += 4) {
        int s0 = esrc[e], s1 = esrc[e + 1], s2 = esrc[e + 2], s3 = esrc[e + 3];
        a0 += bf2f(t[(size_t)s0 * 64 + lane]);
        a1 += bf2f(t[(size_t)s1 * 64 + lane]);
        a2 += bf2f(t[(size_t)s2 * 64 + lane]);
        a3 += bf2f(t[(size_t)s3 * 64 + lane]);
    }
    for (; e < end; e++) a0 += bf2f(t[(size_t)esrc[e] * 64 + lane]);
    float o = fmaxf((a0 + a1 + a2 + a3) * norm_in[wid] + bias[lane], 0.f);
    out[(size_t)wid * 64 + lane] = o;
}

// ---------------------------------------------------------------------------
// 7) per-graph sums exploiting sorted graph_ids
__global__ __launch_bounds__(256) void readout_partial(
        const float* __restrict__ h, const int* __restrict__ gids,
        float* __restrict__ sums, float* __restrict__ counts, int n) {
    const int wid  = (blockIdx.x * blockDim.x + threadIdx.x) >> 6;
    const int lane = threadIdx.x & 63;
    const int beg = wid * 64;
    if (beg >= n) return;
    const int end = min(beg + 64, n);
    int cur = gids[beg];
    float acc = 0.f; int cnt = 0;
    for (int i = beg; i < end; i++) {
        int g = gids[i];               // uniform across wave
        if (g != cur) {
            atomicAdd(&sums[(size_t)cur * 64 + lane], acc);
            if (lane == 0) atomicAdd(&counts[cur], (float)cnt);
            cur = g; acc = 0.f; cnt = 0;
        }
        acc += h[(size_t)i * 64 + lane];
        cnt++;
    }
    atomicAdd(&sums[(size_t)cur * 64 + lane], acc);
    if (lane == 0) atomicAdd(&counts[cur], (float)cnt);
}

__global__ void finalize_kernel(const float* __restrict__ sums, const float* __restrict__ counts,
                                float* __restrict__ out, int total) {
    int i = blockIdx.x * blockDim.x + threadIdx.x;
    if (i < total) out[i] = sums[i] / fmaxf(counts[i >> 6], 1.f);
}

// ---------------------------------------------------------------------------
extern "C" void kernel_launch(void* const* d_in, const int* in_sizes, int n_in,
                              void* d_out, int out_size, void* d_ws, size_t ws_size,
                              hipStream_t stream) {
    const float* n_feat = (const float*)d_in[0];
    const float* W0 = (const float*)d_in[1];
    const float* b0 = (const float*)d_in[2];
    const float* W1 = (const float*)d_in[3];
    const float* b1 = (const float*)d_in[4];
    const float* W2 = (const float*)d_in[5];
    const float* b2 = (const float*)d_in[6];
    const int* src  = (const int*)d_in[7];
    const int* dst  = (const int*)d_in[8];
    const int* gids = (const int*)d_in[9];
    float* out = (float*)d_out;

    char* ws = (char*)d_ws;
    // layout (bytes):
    int*            esrc       = (int*)   (ws + 0);         // E ints (3.2 MB)
    float*          norm_out   = (float*) (ws + 3200000);   // NN floats
    float*          norm_in    = (float*) (ws + 3400000);   // NN floats
    int*            deg_in_tot = (int*)   (ws + 3600000);   // NN ints
    int*            row_ptr    = (int*)   (ws + 3800000);   // NN+1 ints
    int*            bsum       = (int*)   (ws + 4000064);   // SCB ints
    float*          sums       = (float*) (ws + 4200064);   // 500*64 floats
    float*          counts     = (float*) (ws + 4328064);   // 500 floats
    unsigned short* bufA       = (unsigned short*)(ws + 4330112);  // NN*128 bf16 (12.8 MB)
    // degree partials overlay bufA (dead before first gemm writes bufA)
    int*            pin        = (int*)   (ws + 4330112);           // NC*NN ints
    int*            pout       = (int*)   (ws + 4330112 + 6400000); // NC*NN ints
    int*            pcur       = (int*)   (ws + 17200000);  // NC*NN ints (6.4 MB)
    unsigned short* bufB16     = (unsigned short*)(ws + 29930112);  // NN*128 bf16 (h1/h2)
    float*          bufBf      = (float*) (ws + 29930112);  // NN*64 f32 (h3)

    // zero readout accumulators (ws is poisoned 0xAA each call)
    hipMemsetAsync(sums, 0, (NG * 64 + NG) * sizeof(float), stream);

    // graph structure (device-side, every call) — zero global atomics anywhere
    degree_lds_kernel<<<NR * NC, 256, 0, stream>>>(src, dst, pin, pout);
    reduce_norms_kernel<<<(NN + 255) / 256, 256, 0, stream>>>(pin, pout, deg_in_tot,
                                                              norm_in, norm_out, NN);
    scan_block_sums<<<SCB, 1024, 0, stream>>>(deg_in_tot, bsum, NN);
    scan_apply<<<SCB, 1024, 0, stream>>>(deg_in_tot, bsum, pin, row_ptr, pcur, NN);
    place_lds_kernel<<<NR * NC, 256, 0, stream>>>(src, dst, pcur, esrc);

    const int g128 = (NN + 127) / 128;   // gemm <128,128>
    const int g64  = (NN + 255) / 256;   // gemm <64,256>
    const int agg_grid = (NN + 3) / 4;   // 4 waves/block, 1 wave/node

    // layer 1: t0 = bf16((n_feat*norm_out)@W0) ; h1 = bf16(relu(norm_in*agg(t0)+b0))
    gemm_reg_bf<128, 128, false><<<g128, 256, 0, stream>>>(n_feat, W0, norm_out, bufA, NN);
    aggregate128_h16<<<agg_grid, 256, 0, stream>>>(bufA, row_ptr, esrc, norm_in, b0, bufB16, NN);
    // layer 2 (bf16 A)
    gemm_reg_bf<128, 128, true><<<g128, 256, 0, stream>>>(bufB16, W1, norm_out, bufA, NN);
    aggregate128_h16<<<agg_grid, 256, 0, stream>>>(bufA, row_ptr, esrc, norm_in, b1, bufB16, NN);
    // layer 3 (bf16 A, 64-wide out)
    gemm_reg_bf<64, 256, true><<<g64, 256, 0, stream>>>(bufB16, W2, norm_out, bufA, NN);
    aggregate64_f32<<<agg_grid, 256, 0, stream>>>(bufA, row_ptr, esrc, norm_in, b2, bufBf, NN);

    // readout: per-graph mean (graph_ids sorted)
    const int ro_threads = ((NN + 63) / 64) * 64;
    readout_partial<<<(ro_threads + 255) / 256, 256, 0, stream>>>(bufBf, gids, sums, counts, NN);
    finalize_kernel<<<(NG * 64 + 255) / 256, 256, 0, stream>>>(sums, counts, out, NG * 64);
}

// Round 12
// 377.184 us; speedup vs baseline: 1.1192x; 1.1192x over previous
//
#include <hip/hip_runtime.h>
#include <hip/hip_bf16.h>

// Problem constants (match reference)
#define NN 50000
#define NE 800000
#define NG 500
// D_IN = D_HID = 128, D_OUT = 64

// degree/placement decomposition
#define NR 8            // node ranges (LDS histogram = 2 x NN/NR ints = 50 KB)
#define NC 32           // edge chunks
#define RNG (NN / NR)   // 6250 nodes per range
#define CHE (NE / NC)   // 25000 edges per chunk
#define SCB 13          // scan blocks: ceil(NN / 4096)

// bf16 helpers (RNE pack, shift-unpack)
__device__ __forceinline__ unsigned f2bf(float f) {
    unsigned u = __float_as_uint(f);
    return (u + 0x7fffu + ((u >> 16) & 1u)) >> 16;
}
__device__ __forceinline__ float bf2f(unsigned u16) {
    return __uint_as_float(u16 << 16);
}

// ---------------------------------------------------------------------------
// 1) degree count with ZERO global atomics: LDS histograms + non-atomic flush.
__global__ __launch_bounds__(256) void degree_lds_kernel(
        const int* __restrict__ src, const int* __restrict__ dst,
        int* __restrict__ pin, int* __restrict__ pout) {
    __shared__ int hin[RNG], hout[RNG];
    const int tid   = threadIdx.x;
    const int r     = blockIdx.x & (NR - 1);
    const int c     = blockIdx.x / NR;
    const int rbase = r * RNG;
    for (int i = tid; i < RNG; i += 256) { hin[i] = 0; hout[i] = 0; }
    __syncthreads();
    const int4* s4 = (const int4*)(src + c * CHE);
    const int4* d4 = (const int4*)(dst + c * CHE);
    for (int i = tid; i < CHE / 4; i += 256) {
        int4 s = s4[i];
        int4 d = d4[i];
        unsigned a;
        a = (unsigned)(d.x - rbase); if (a < RNG) atomicAdd(&hin[a], 1);
        a = (unsigned)(d.y - rbase); if (a < RNG) atomicAdd(&hin[a], 1);
        a = (unsigned)(d.z - rbase); if (a < RNG) atomicAdd(&hin[a], 1);
        a = (unsigned)(d.w - rbase); if (a < RNG) atomicAdd(&hin[a], 1);
        a = (unsigned)(s.x - rbase); if (a < RNG) atomicAdd(&hout[a], 1);
        a = (unsigned)(s.y - rbase); if (a < RNG) atomicAdd(&hout[a], 1);
        a = (unsigned)(s.z - rbase); if (a < RNG) atomicAdd(&hout[a], 1);
        a = (unsigned)(s.w - rbase); if (a < RNG) atomicAdd(&hout[a], 1);
    }
    __syncthreads();
    for (int i = tid; i < RNG; i += 256) {
        pin [c * NN + rbase + i] = hin[i];
        pout[c * NN + rbase + i] = hout[i];
    }
}

// ---------------------------------------------------------------------------
// 2) reduce partials -> total in-degree + both norms (fused)
__global__ void reduce_norms_kernel(const int* __restrict__ pin, const int* __restrict__ pout,
                                    int* __restrict__ deg_in_tot,
                                    float* __restrict__ norm_in,
                                    float* __restrict__ norm_out, int n) {
    int i = blockIdx.x * blockDim.x + threadIdx.x;
    if (i >= n) return;
    int di = 0, dq = 0;
    #pragma unroll
    for (int c = 0; c < NC; c++) {
        di += pin [c * NN + i];
        dq += pout[c * NN + i];
    }
    deg_in_tot[i] = di;
    norm_in[i]  = di > 0 ? 1.0f / sqrtf((float)di) : 0.f;
    norm_out[i] = dq > 0 ? 1.0f / sqrtf((float)dq) : 0.f;
}

// ---------------------------------------------------------------------------
// 3a) per-4096-chunk sums (parallel scan, phase 1)
__global__ __launch_bounds__(1024) void scan_block_sums(
        const int* __restrict__ deg, int* __restrict__ bsum, int n) {
    __shared__ int wsum[16];
    const int tid = threadIdx.x, lane = tid & 63, wv = tid >> 6;
    const int i0 = blockIdx.x * 4096 + tid * 4;
    int s = 0;
    if (i0 + 3 < n) {
        int4 v = *(const int4*)(deg + i0);
        s = v.x + v.y + v.z + v.w;
    } else if (i0 < n) {
        s = deg[i0];
        if (i0 + 1 < n) s += deg[i0 + 1];
        if (i0 + 2 < n) s += deg[i0 + 2];
    }
    #pragma unroll
    for (int off = 32; off > 0; off >>= 1) s += __shfl_down(s, off);
    if (lane == 0) wsum[wv] = s;
    __syncthreads();
    if (wv == 0) {
        int t = (lane < 16) ? wsum[lane] : 0;
        #pragma unroll
        for (int off = 8; off > 0; off >>= 1) t += __shfl_down(t, off);
        if (lane == 0) bsum[blockIdx.x] = t;
    }
}

// 3b) per-chunk local scan + global base -> row_ptr ONLY (tiny traffic; the
//     heavy pcur walk lives in chunk_offsets_kernel at full parallelism).
__global__ __launch_bounds__(1024) void scan_apply(
        const int* __restrict__ deg, const int* __restrict__ bsum,
        int* __restrict__ row_ptr, int n) {
    __shared__ int wsum[16];
    const int tid = threadIdx.x, lane = tid & 63, wv = tid >> 6;
    const int b = blockIdx.x;
    int base = 0;
    for (int j = 0; j < SCB; j++) base += (j < b) ? bsum[j] : 0;
    const int i0 = b * 4096 + tid * 4;
    int v0 = 0, v1 = 0, v2 = 0, v3 = 0;
    if (i0 + 3 < n) {
        int4 v = *(const int4*)(deg + i0);
        v0 = v.x; v1 = v.y; v2 = v.z; v3 = v.w;
    } else if (i0 < n) {
        v0 = deg[i0];
        if (i0 + 1 < n) v1 = deg[i0 + 1];
        if (i0 + 2 < n) v2 = deg[i0 + 2];
    }
    const int l0 = v0, l1 = l0 + v1, l2 = l1 + v2, l3 = l2 + v3;
    int x = l3;
    #pragma unroll
    for (int off = 1; off < 64; off <<= 1) {
        int y = __shfl_up(x, off);
        if (lane >= off) x += y;
    }
    if (lane == 63) wsum[wv] = x;
    __syncthreads();
    if (wv == 0) {
        int t = (lane < 16) ? wsum[lane] : 0;
        int s = t;
        #pragma unroll
        for (int off = 1; off < 16; off <<= 1) {
            int y = __shfl_up(s, off);
            if (lane >= off) s += y;
        }
        if (lane < 16) wsum[lane] = s - t;   // exclusive wave offsets
    }
    __syncthreads();
    const int pre = base + wsum[wv] + (x - l3);  // global exclusive prefix at i0
    if (b == 0 && tid == 0) row_ptr[0] = 0;
    if (i0 < n)     row_ptr[i0 + 1] = pre + l0;
    if (i0 + 1 < n) row_ptr[i0 + 2] = pre + l1;
    if (i0 + 2 < n) row_ptr[i0 + 3] = pre + l2;
    if (i0 + 3 < n) row_ptr[i0 + 4] = pre + l3;
}

// 3c) per-(node,chunk) placement offsets at full parallelism (196 blocks):
//     pcur[c][i] = row_ptr[i] + prefix_c(pin[.][i])
__global__ void chunk_offsets_kernel(const int* __restrict__ pin,
                                     const int* __restrict__ row_ptr,
                                     int* __restrict__ pcur, int n) {
    int i = blockIdx.x * blockDim.x + threadIdx.x;
    if (i >= n) return;
    int off = row_ptr[i];
    #pragma unroll
    for (int c = 0; c < NC; c++) {
        pcur[c * NN + i] = off;
        off += pin[c * NN + i];
    }
}

// ---------------------------------------------------------------------------
// 4) CSR placement with ZERO global atomics: LDS cursors per (range,chunk).
__global__ __launch_bounds__(256) void place_lds_kernel(
        const int* __restrict__ src, const int* __restrict__ dst,
        const int* __restrict__ pcur, int* __restrict__ esrc) {
    __shared__ int lcur[RNG];
    const int tid   = threadIdx.x;
    const int r     = blockIdx.x & (NR - 1);
    const int c     = blockIdx.x / NR;
    const int rbase = r * RNG;
    for (int i = tid; i < RNG; i += 256) lcur[i] = pcur[c * NN + rbase + i];
    __syncthreads();
    const int4* s4 = (const int4*)(src + c * CHE);
    const int4* d4 = (const int4*)(dst + c * CHE);
    for (int i = tid; i < CHE / 4; i += 256) {
        int4 s = s4[i];
        int4 d = d4[i];
        unsigned a;
        a = (unsigned)(d.x - rbase); if (a < RNG) esrc[atomicAdd(&lcur[a], 1)] = s.x;
        a = (unsigned)(d.y - rbase); if (a < RNG) esrc[atomicAdd(&lcur[a], 1)] = s.y;
        a = (unsigned)(d.z - rbase); if (a < RNG) esrc[atomicAdd(&lcur[a], 1)] = s.z;
        a = (unsigned)(d.w - rbase); if (a < RNG) esrc[atomicAdd(&lcur[a], 1)] = s.w;
    }
}

// ---------------------------------------------------------------------------
// 5) GEMM: out = bf16((A*norm) @ W).  A is f32 (layer 1) or bf16 (layers 2,3).
template<int DO, int ROWS, bool A16>
__global__ __launch_bounds__(256) void gemm_reg_bf(
        const void* __restrict__ Av, const float* __restrict__ W,
        const float* __restrict__ norm, unsigned short* __restrict__ out, int nrows) {
    constexpr int DI  = 128;
    constexpr int KC  = 32;          // K-chunk
    constexpr int CXN = DO / 8;      // col-threads
    constexpr int RYN = 256 / CXN;   // row-threads; ROWS = RYN*8
    static_assert(ROWS == RYN * 8, "tile mismatch");
    __shared__ float At[KC][ROWS + 4];
    __shared__ float Wl[KC][DO + 4];

    const int tid  = threadIdx.x;
    const int cx   = tid % CXN;
    const int ry   = tid / CXN;
    const int row0 = blockIdx.x * ROWS;

    float acc[8][8] = {};

    for (int kc = 0; kc < DI; kc += KC) {
        __syncthreads();
        constexpr int AF4 = ROWS * KC / 4;
        #pragma unroll
        for (int i = tid; i < AF4; i += 256) {
            int r  = i >> 3;
            int kq = i & 7;
            int gr = row0 + r;
            float v0 = 0.f, v1 = 0.f, v2 = 0.f, v3 = 0.f;
            if (gr < nrows) {
                float s = norm[gr];
                if constexpr (A16) {
                    const unsigned short* A = (const unsigned short*)Av;
                    uint2 u = *(const uint2*)(A + (size_t)gr * DI + kc + kq * 4);
                    v0 = bf2f(u.x & 0xffffu) * s; v1 = bf2f(u.x >> 16) * s;
                    v2 = bf2f(u.y & 0xffffu) * s; v3 = bf2f(u.y >> 16) * s;
                } else {
                    const float* A = (const float*)Av;
                    float4 v = ((const float4*)(A + (size_t)gr * DI + kc))[kq];
                    v0 = v.x * s; v1 = v.y * s; v2 = v.z * s; v3 = v.w * s;
                }
            }
            At[kq * 4 + 0][r] = v0;
            At[kq * 4 + 1][r] = v1;
            At[kq * 4 + 2][r] = v2;
            At[kq * 4 + 3][r] = v3;
        }
        constexpr int WF4 = KC * DO / 4;
        #pragma unroll
        for (int i = tid; i < WF4; i += 256) {
            int k  = i / (DO / 4);
            int c4 = i % (DO / 4);
            *(float4*)&Wl[k][c4 * 4] = ((const float4*)(W + (size_t)(kc + k) * DO))[c4];
        }
        __syncthreads();
        #pragma unroll 4
        for (int k = 0; k < KC; k++) {
            float a[8], w[8];
            *(float4*)&a[0] = *(const float4*)&At[k][ry * 4];
            *(float4*)&a[4] = *(const float4*)&At[k][ROWS / 2 + ry * 4];
            *(float4*)&w[0] = *(const float4*)&Wl[k][cx * 4];
            *(float4*)&w[4] = *(const float4*)&Wl[k][DO / 2 + cx * 4];
            #pragma unroll
            for (int i = 0; i < 8; i++)
                #pragma unroll
                for (int j = 0; j < 8; j++)
                    acc[i][j] += a[i] * w[j];
        }
    }
    #pragma unroll
    for (int i = 0; i < 8; i++) {
        int r  = (i < 4) ? (ry * 4 + i) : (ROWS / 2 + ry * 4 + (i - 4));
        int gr = row0 + r;
        if (gr < nrows) {
            unsigned short* orow = out + (size_t)gr * DO;
            uint2 lo, hi;
            lo.x = f2bf(acc[i][0]) | (f2bf(acc[i][1]) << 16);
            lo.y = f2bf(acc[i][2]) | (f2bf(acc[i][3]) << 16);
            hi.x = f2bf(acc[i][4]) | (f2bf(acc[i][5]) << 16);
            hi.y = f2bf(acc[i][6]) | (f2bf(acc[i][7]) << 16);
            ((uint2*)orow)[cx]            = lo;   // cols cx*4..+3
            ((uint2*)(orow + DO / 2))[cx] = hi;   // cols DO/2+cx*4..+3
        }
    }
}

// ---------------------------------------------------------------------------
// 6a) 128-wide pull-aggregation, bf16 table in, bf16 h out (f32 accum).
__global__ __launch_bounds__(256) void aggregate128_h16(
        const unsigned short* __restrict__ t, const int* __restrict__ row_ptr,
        const int* __restrict__ esrc, const float* __restrict__ norm_in,
        const float* __restrict__ bias, unsigned short* __restrict__ out, int n) {
    const int wid  = (blockIdx.x * blockDim.x + threadIdx.x) >> 6;
    const int lane = threadIdx.x & 63;
    if (wid >= n) return;
    const int beg = row_ptr[wid], end = row_ptr[wid + 1];
    const unsigned* tp = (const unsigned*)t;   // 64 uints per row
    float ax0 = 0, ay0 = 0, ax1 = 0, ay1 = 0, ax2 = 0, ay2 = 0, ax3 = 0, ay3 = 0;
    int e = beg;
    for (; e + 3 < end; e += 4) {
        int s0 = esrc[e], s1 = esrc[e + 1], s2 = esrc[e + 2], s3 = esrc[e + 3];
        unsigned v0 = tp[(size_t)s0 * 64 + lane];
        unsigned v1 = tp[(size_t)s1 * 64 + lane];
        unsigned v2 = tp[(size_t)s2 * 64 + lane];
        unsigned v3 = tp[(size_t)s3 * 64 + lane];
        ax0 += bf2f(v0 & 0xffffu); ay0 += bf2f(v0 >> 16);
        ax1 += bf2f(v1 & 0xffffu); ay1 += bf2f(v1 >> 16);
        ax2 += bf2f(v2 & 0xffffu); ay2 += bf2f(v2 >> 16);
        ax3 += bf2f(v3 & 0xffffu); ay3 += bf2f(v3 >> 16);
    }
    for (; e < end; e++) {
        unsigned v = tp[(size_t)esrc[e] * 64 + lane];
        ax0 += bf2f(v & 0xffffu); ay0 += bf2f(v >> 16);
    }
    float ni = norm_in[wid];
    float2 bb = ((const float2*)bias)[lane];
    float ox = fmaxf((ax0 + ax1 + ax2 + ax3) * ni + bb.x, 0.f);
    float oy = fmaxf((ay0 + ay1 + ay2 + ay3) * ni + bb.y, 0.f);
    ((unsigned*)out)[(size_t)wid * 64 + lane] = f2bf(ox) | (f2bf(oy) << 16);
}

// 6b) 64-wide pull-aggregation, bf16 table in, f32 out (feeds readout).
__global__ __launch_bounds__(256) void aggregate64_f32(
        const unsigned short* __restrict__ t, const int* __restrict__ row_ptr,
        const int* __restrict__ esrc, const float* __restrict__ norm_in,
        const float* __restrict__ bias, float* __restrict__ out, int n) {
    const int wid  = (blockIdx.x * blockDim.x + threadIdx.x) >> 6;
    const int lane = threadIdx.x & 63;
    if (wid >= n) return;
    const int beg = row_ptr[wid], end = row_ptr[wid + 1];
    float a0 = 0, a1 = 0, a2 = 0, a3 = 0;
    int e = beg;
    for (; e + 3 < end; e += 4) {
        int s0 = esrc[e], s1 = esrc[e + 1], s2 = esrc[e + 2], s3 = esrc[e + 3];
        a0 += bf2f(t[(size_t)s0 * 64 + lane]);
        a1 += bf2f(t[(size_t)s1 * 64 + lane]);
        a2 += bf2f(t[(size_t)s2 * 64 + lane]);
        a3 += bf2f(t[(size_t)s3 * 64 + lane]);
    }
    for (; e < end; e++) a0 += bf2f(t[(size_t)esrc[e] * 64 + lane]);
    float o = fmaxf((a0 + a1 + a2 + a3) * norm_in[wid] + bias[lane], 0.f);
    out[(size_t)wid * 64 + lane] = o;
}

// ---------------------------------------------------------------------------
// 7) per-graph sums exploiting sorted graph_ids
__global__ __launch_bounds__(256) void readout_partial(
        const float* __restrict__ h, const int* __restrict__ gids,
        float* __restrict__ sums, float* __restrict__ counts, int n) {
    const int wid  = (blockIdx.x * blockDim.x + threadIdx.x) >> 6;
    const int lane = threadIdx.x & 63;
    const int beg = wid * 64;
    if (beg >= n) return;
    const int end = min(beg + 64, n);
    int cur = gids[beg];
    float acc = 0.f; int cnt = 0;
    for (int i = beg; i < end; i++) {
        int g = gids[i];               // uniform across wave
        if (g != cur) {
            atomicAdd(&sums[(size_t)cur * 64 + lane], acc);
            if (lane == 0) atomicAdd(&counts[cur], (float)cnt);
            cur = g; acc = 0.f; cnt = 0;
        }
        acc += h[(size_t)i * 64 + lane];
        cnt++;
    }
    atomicAdd(&sums[(size_t)cur * 64 + lane], acc);
    if (lane == 0) atomicAdd(&counts[cur], (float)cnt);
}

__global__ void finalize_kernel(const float* __restrict__ sums, const float* __restrict__ counts,
                                float* __restrict__ out, int total) {
    int i = blockIdx.x * blockDim.x + threadIdx.x;
    if (i < total) out[i] = sums[i] / fmaxf(counts[i >> 6], 1.f);
}

// ---------------------------------------------------------------------------
extern "C" void kernel_launch(void* const* d_in, const int* in_sizes, int n_in,
                              void* d_out, int out_size, void* d_ws, size_t ws_size,
                              hipStream_t stream) {
    const float* n_feat = (const float*)d_in[0];
    const float* W0 = (const float*)d_in[1];
    const float* b0 = (const float*)d_in[2];
    const float* W1 = (const float*)d_in[3];
    const float* b1 = (const float*)d_in[4];
    const float* W2 = (const float*)d_in[5];
    const float* b2 = (const float*)d_in[6];
    const int* src  = (const int*)d_in[7];
    const int* dst  = (const int*)d_in[8];
    const int* gids = (const int*)d_in[9];
    float* out = (float*)d_out;

    char* ws = (char*)d_ws;
    // layout (bytes):
    int*            esrc       = (int*)   (ws + 0);         // E ints (3.2 MB)
    float*          norm_out   = (float*) (ws + 3200000);   // NN floats
    float*          norm_in    = (float*) (ws + 3400000);   // NN floats
    int*            deg_in_tot = (int*)   (ws + 3600000);   // NN ints
    int*            row_ptr    = (int*)   (ws + 3800000);   // NN+1 ints
    int*            bsum       = (int*)   (ws + 4000064);   // SCB ints
    float*          sums       = (float*) (ws + 4200064);   // 500*64 floats
    float*          counts     = (float*) (ws + 4328064);   // 500 floats
    unsigned short* bufA       = (unsigned short*)(ws + 4330112);  // NN*128 bf16 (12.8 MB)
    // degree partials overlay bufA (dead before first gemm writes bufA)
    int*            pin        = (int*)   (ws + 4330112);           // NC*NN ints
    int*            pout       = (int*)   (ws + 4330112 + 6400000); // NC*NN ints
    int*            pcur       = (int*)   (ws + 17200000);  // NC*NN ints (6.4 MB)
    unsigned short* bufB16     = (unsigned short*)(ws + 29930112);  // NN*128 bf16 (h1/h2)
    float*          bufBf      = (float*) (ws + 29930112);  // NN*64 f32 (h3)

    // zero readout accumulators (ws is poisoned 0xAA each call)
    hipMemsetAsync(sums, 0, (NG * 64 + NG) * sizeof(float), stream);

    // graph structure (device-side, every call) — zero global atomics anywhere
    degree_lds_kernel<<<NR * NC, 256, 0, stream>>>(src, dst, pin, pout);
    reduce_norms_kernel<<<(NN + 255) / 256, 256, 0, stream>>>(pin, pout, deg_in_tot,
                                                              norm_in, norm_out, NN);
    scan_block_sums<<<SCB, 1024, 0, stream>>>(deg_in_tot, bsum, NN);
    scan_apply<<<SCB, 1024, 0, stream>>>(deg_in_tot, bsum, row_ptr, NN);
    chunk_offsets_kernel<<<(NN + 255) / 256, 256, 0, stream>>>(pin, row_ptr, pcur, NN);
    place_lds_kernel<<<NR * NC, 256, 0, stream>>>(src, dst, pcur, esrc);

    const int g128 = (NN + 127) / 128;   // gemm <128,128>
    const int g64  = (NN + 255) / 256;   // gemm <64,256>
    const int agg_grid = (NN + 3) / 4;   // 4 waves/block, 1 wave/node

    // layer 1: t0 = bf16((n_feat*norm_out)@W0) ; h1 = bf16(relu(norm_in*agg(t0)+b0))
    gemm_reg_bf<128, 128, false><<<g128, 256, 0, stream>>>(n_feat, W0, norm_out, bufA, NN);
    aggregate128_h16<<<agg_grid, 256, 0, stream>>>(bufA, row_ptr, esrc, norm_in, b0, bufB16, NN);
    // layer 2 (bf16 A)
    gemm_reg_bf<128, 128, true><<<g128, 256, 0, stream>>>(bufB16, W1, norm_out, bufA, NN);
    aggregate128_h16<<<agg_grid, 256, 0, stream>>>(bufA, row_ptr, esrc, norm_in, b1, bufB16, NN);
    // layer 3 (bf16 A, 64-wide out)
    gemm_reg_bf<64, 256, true><<<g64, 256, 0, stream>>>(bufB16, W2, norm_out, bufA, NN);
    aggregate64_f32<<<agg_grid, 256, 0, stream>>>(bufA, row_ptr, esrc, norm_in, b2, bufBf, NN);

    // readout: per-graph mean (graph_ids sorted)
    const int ro_threads = ((NN + 63) / 64) * 64;
    readout_partial<<<(ro_threads + 255) / 256, 256, 0, stream>>>(bufBf, gids, sums, counts, NN);
    finalize_kernel<<<(NG * 64 + 255) / 256, 256, 0, stream>>>(sums, counts, out, NG * 64);
}

// Round 13
// 359.031 us; speedup vs baseline: 1.1758x; 1.0506x over previous
//
#include <hip/hip_runtime.h>
#include <hip/hip_bf16.h>

// Problem constants (match reference)
#define NN 50000
#define NE 800000
#define NG 500
// D_IN = D_HID = 128, D_OUT = 64

// degree/placement decomposition
#define NR 8            // node ranges (LDS histogram = 2 x NN/NR ints = 50 KB)
#define NC 32           // edge chunks
#define RNG (NN / NR)   // 6250 nodes per range
#define CHE (NE / NC)   // 25000 edges per chunk
#define SCB 13          // scan blocks: ceil(NN / 4096)

// bf16 helpers (RNE pack, shift-unpack)
__device__ __forceinline__ unsigned f2bf(float f) {
    unsigned u = __float_as_uint(f);
    return (u + 0x7fffu + ((u >> 16) & 1u)) >> 16;
}
__device__ __forceinline__ float bf2f(unsigned u16) {
    return __uint_as_float(u16 << 16);
}

// ---------------------------------------------------------------------------
// 1) degree count with ZERO global atomics: LDS histograms + non-atomic flush.
//    Also zeroes bsum (13 ints) for the downstream scan.
__global__ __launch_bounds__(256) void degree_lds_kernel(
        const int* __restrict__ src, const int* __restrict__ dst,
        int* __restrict__ pin, int* __restrict__ pout, int* __restrict__ bsum) {
    __shared__ int hin[RNG], hout[RNG];
    const int tid   = threadIdx.x;
    const int r     = blockIdx.x & (NR - 1);
    const int c     = blockIdx.x / NR;
    const int rbase = r * RNG;
    if (blockIdx.x == 0 && tid < SCB) bsum[tid] = 0;
    for (int i = tid; i < RNG; i += 256) { hin[i] = 0; hout[i] = 0; }
    __syncthreads();
    const int4* s4 = (const int4*)(src + c * CHE);
    const int4* d4 = (const int4*)(dst + c * CHE);
    for (int i = tid; i < CHE / 4; i += 256) {
        int4 s = s4[i];
        int4 d = d4[i];
        unsigned a;
        a = (unsigned)(d.x - rbase); if (a < RNG) atomicAdd(&hin[a], 1);
        a = (unsigned)(d.y - rbase); if (a < RNG) atomicAdd(&hin[a], 1);
        a = (unsigned)(d.z - rbase); if (a < RNG) atomicAdd(&hin[a], 1);
        a = (unsigned)(d.w - rbase); if (a < RNG) atomicAdd(&hin[a], 1);
        a = (unsigned)(s.x - rbase); if (a < RNG) atomicAdd(&hout[a], 1);
        a = (unsigned)(s.y - rbase); if (a < RNG) atomicAdd(&hout[a], 1);
        a = (unsigned)(s.z - rbase); if (a < RNG) atomicAdd(&hout[a], 1);
        a = (unsigned)(s.w - rbase); if (a < RNG) atomicAdd(&hout[a], 1);
    }
    __syncthreads();
    for (int i = tid; i < RNG; i += 256) {
        pin [c * NN + rbase + i] = hin[i];
        pout[c * NN + rbase + i] = hout[i];
    }
}

// ---------------------------------------------------------------------------
// 2) reduce partials -> deg_in_tot + norms, PLUS per-4096-chunk sums into bsum
//    (block-reduce + 1 atomic/block; 16 blocks per chunk), PLUS zero sums/counts.
__global__ __launch_bounds__(256) void reduce_norms_kernel(
        const int* __restrict__ pin, const int* __restrict__ pout,
        int* __restrict__ deg_in_tot, float* __restrict__ norm_in,
        float* __restrict__ norm_out, int* __restrict__ bsum,
        float* __restrict__ sums, int n) {
    const int tid = threadIdx.x, lane = tid & 63, wv = tid >> 6;
    const int i = blockIdx.x * 256 + tid;
    const int gi = i;
    if (gi < NG * 64 + NG) sums[gi] = 0.f;   // zero sums+counts (contiguous)
    int di = 0, dq = 0;
    if (i < n) {
        #pragma unroll
        for (int c = 0; c < NC; c++) {
            di += pin [c * NN + i];
            dq += pout[c * NN + i];
        }
        deg_in_tot[i] = di;
        norm_in[i]  = di > 0 ? 1.0f / sqrtf((float)di) : 0.f;
        norm_out[i] = dq > 0 ? 1.0f / sqrtf((float)dq) : 0.f;
    }
    // block sum of di -> bsum[chunk]  (block fully inside one 4096-chunk)
    __shared__ int wsum[4];
    int s = di;
    #pragma unroll
    for (int off = 32; off > 0; off >>= 1) s += __shfl_down(s, off);
    if (lane == 0) wsum[wv] = s;
    __syncthreads();
    if (tid == 0) {
        int t = wsum[0] + wsum[1] + wsum[2] + wsum[3];
        atomicAdd(&bsum[blockIdx.x >> 4], t);
    }
}

// ---------------------------------------------------------------------------
// 3) per-chunk local scan + global base -> row_ptr (tiny traffic, 13 blocks)
__global__ __launch_bounds__(1024) void scan_apply(
        const int* __restrict__ deg, const int* __restrict__ bsum,
        int* __restrict__ row_ptr, int n) {
    __shared__ int wsum[16];
    const int tid = threadIdx.x, lane = tid & 63, wv = tid >> 6;
    const int b = blockIdx.x;
    int base = 0;
    for (int j = 0; j < SCB; j++) base += (j < b) ? bsum[j] : 0;
    const int i0 = b * 4096 + tid * 4;
    int v0 = 0, v1 = 0, v2 = 0, v3 = 0;
    if (i0 + 3 < n) {
        int4 v = *(const int4*)(deg + i0);
        v0 = v.x; v1 = v.y; v2 = v.z; v3 = v.w;
    } else if (i0 < n) {
        v0 = deg[i0];
        if (i0 + 1 < n) v1 = deg[i0 + 1];
        if (i0 + 2 < n) v2 = deg[i0 + 2];
    }
    const int l0 = v0, l1 = l0 + v1, l2 = l1 + v2, l3 = l2 + v3;
    int x = l3;
    #pragma unroll
    for (int off = 1; off < 64; off <<= 1) {
        int y = __shfl_up(x, off);
        if (lane >= off) x += y;
    }
    if (lane == 63) wsum[wv] = x;
    __syncthreads();
    if (wv == 0) {
        int t = (lane < 16) ? wsum[lane] : 0;
        int s = t;
        #pragma unroll
        for (int off = 1; off < 16; off <<= 1) {
            int y = __shfl_up(s, off);
            if (lane >= off) s += y;
        }
        if (lane < 16) wsum[lane] = s - t;   // exclusive wave offsets
    }
    __syncthreads();
    const int pre = base + wsum[wv] + (x - l3);  // global exclusive prefix at i0
    if (b == 0 && tid == 0) row_ptr[0] = 0;
    if (i0 < n)     row_ptr[i0 + 1] = pre + l0;
    if (i0 + 1 < n) row_ptr[i0 + 2] = pre + l1;
    if (i0 + 2 < n) row_ptr[i0 + 3] = pre + l2;
    if (i0 + 3 < n) row_ptr[i0 + 4] = pre + l3;
}

// 3c) per-(node,chunk) placement offsets at full parallelism (196 blocks)
__global__ void chunk_offsets_kernel(const int* __restrict__ pin,
                                     const int* __restrict__ row_ptr,
                                     int* __restrict__ pcur, int n) {
    int i = blockIdx.x * blockDim.x + threadIdx.x;
    if (i >= n) return;
    int off = row_ptr[i];
    #pragma unroll
    for (int c = 0; c < NC; c++) {
        pcur[c * NN + i] = off;
        off += pin[c * NN + i];
    }
}

// ---------------------------------------------------------------------------
// 4) CSR placement with ZERO global atomics: LDS cursors per (range,chunk).
__global__ __launch_bounds__(256) void place_lds_kernel(
        const int* __restrict__ src, const int* __restrict__ dst,
        const int* __restrict__ pcur, int* __restrict__ esrc) {
    __shared__ int lcur[RNG];
    const int tid   = threadIdx.x;
    const int r     = blockIdx.x & (NR - 1);
    const int c     = blockIdx.x / NR;
    const int rbase = r * RNG;
    for (int i = tid; i < RNG; i += 256) lcur[i] = pcur[c * NN + rbase + i];
    __syncthreads();
    const int4* s4 = (const int4*)(src + c * CHE);
    const int4* d4 = (const int4*)(dst + c * CHE);
    for (int i = tid; i < CHE / 4; i += 256) {
        int4 s = s4[i];
        int4 d = d4[i];
        unsigned a;
        a = (unsigned)(d.x - rbase); if (a < RNG) esrc[atomicAdd(&lcur[a], 1)] = s.x;
        a = (unsigned)(d.y - rbase); if (a < RNG) esrc[atomicAdd(&lcur[a], 1)] = s.y;
        a = (unsigned)(d.z - rbase); if (a < RNG) esrc[atomicAdd(&lcur[a], 1)] = s.z;
        a = (unsigned)(d.w - rbase); if (a < RNG) esrc[atomicAdd(&lcur[a], 1)] = s.w;
    }
}

// ---------------------------------------------------------------------------
// 5) GEMM: out = bf16((A*norm) @ W).  A is f32 (layer 1) or bf16 (layers 2,3).
template<int DO, int ROWS, bool A16>
__global__ __launch_bounds__(256) void gemm_reg_bf(
        const void* __restrict__ Av, const float* __restrict__ W,
        const float* __restrict__ norm, unsigned short* __restrict__ out, int nrows) {
    constexpr int DI  = 128;
    constexpr int KC  = 32;          // K-chunk
    constexpr int CXN = DO / 8;      // col-threads
    constexpr int RYN = 256 / CXN;   // row-threads; ROWS = RYN*8
    static_assert(ROWS == RYN * 8, "tile mismatch");
    __shared__ float At[KC][ROWS + 4];
    __shared__ float Wl[KC][DO + 4];

    const int tid  = threadIdx.x;
    const int cx   = tid % CXN;
    const int ry   = tid / CXN;
    const int row0 = blockIdx.x * ROWS;

    float acc[8][8] = {};

    for (int kc = 0; kc < DI; kc += KC) {
        __syncthreads();
        constexpr int AF4 = ROWS * KC / 4;
        #pragma unroll
        for (int i = tid; i < AF4; i += 256) {
            int r  = i >> 3;
            int kq = i & 7;
            int gr = row0 + r;
            float v0 = 0.f, v1 = 0.f, v2 = 0.f, v3 = 0.f;
            if (gr < nrows) {
                float s = norm[gr];
                if constexpr (A16) {
                    const unsigned short* A = (const unsigned short*)Av;
                    uint2 u = *(const uint2*)(A + (size_t)gr * DI + kc + kq * 4);
                    v0 = bf2f(u.x & 0xffffu) * s; v1 = bf2f(u.x >> 16) * s;
                    v2 = bf2f(u.y & 0xffffu) * s; v3 = bf2f(u.y >> 16) * s;
                } else {
                    const float* A = (const float*)Av;
                    float4 v = ((const float4*)(A + (size_t)gr * DI + kc))[kq];
                    v0 = v.x * s; v1 = v.y * s; v2 = v.z * s; v3 = v.w * s;
                }
            }
            At[kq * 4 + 0][r] = v0;
            At[kq * 4 + 1][r] = v1;
            At[kq * 4 + 2][r] = v2;
            At[kq * 4 + 3][r] = v3;
        }
        constexpr int WF4 = KC * DO / 4;
        #pragma unroll
        for (int i = tid; i < WF4; i += 256) {
            int k  = i / (DO / 4);
            int c4 = i % (DO / 4);
            *(float4*)&Wl[k][c4 * 4] = ((const float4*)(W + (size_t)(kc + k) * DO))[c4];
        }
        __syncthreads();
        #pragma unroll 4
        for (int k = 0; k < KC; k++) {
            float a[8], w[8];
            *(float4*)&a[0] = *(const float4*)&At[k][ry * 4];
            *(float4*)&a[4] = *(const float4*)&At[k][ROWS / 2 + ry * 4];
            *(float4*)&w[0] = *(const float4*)&Wl[k][cx * 4];
            *(float4*)&w[4] = *(const float4*)&Wl[k][DO / 2 + cx * 4];
            #pragma unroll
            for (int i = 0; i < 8; i++)
                #pragma unroll
                for (int j = 0; j < 8; j++)
                    acc[i][j] += a[i] * w[j];
        }
    }
    #pragma unroll
    for (int i = 0; i < 8; i++) {
        int r  = (i < 4) ? (ry * 4 + i) : (ROWS / 2 + ry * 4 + (i - 4));
        int gr = row0 + r;
        if (gr < nrows) {
            unsigned short* orow = out + (size_t)gr * DO;
            uint2 lo, hi;
            lo.x = f2bf(acc[i][0]) | (f2bf(acc[i][1]) << 16);
            lo.y = f2bf(acc[i][2]) | (f2bf(acc[i][3]) << 16);
            hi.x = f2bf(acc[i][4]) | (f2bf(acc[i][5]) << 16);
            hi.y = f2bf(acc[i][6]) | (f2bf(acc[i][7]) << 16);
            ((uint2*)orow)[cx]            = lo;   // cols cx*4..+3
            ((uint2*)(orow + DO / 2))[cx] = hi;   // cols DO/2+cx*4..+3
        }
    }
}

// ---------------------------------------------------------------------------
// 6a) 128-wide pull-aggregation, 8 gathers in flight (latency hiding).
__global__ __launch_bounds__(256) void aggregate128_h16(
        const unsigned short* __restrict__ t, const int* __restrict__ row_ptr,
        const int* __restrict__ esrc, const float* __restrict__ norm_in,
        const float* __restrict__ bias, unsigned short* __restrict__ out, int n) {
    const int wid  = (blockIdx.x * blockDim.x + threadIdx.x) >> 6;
    const int lane = threadIdx.x & 63;
    if (wid >= n) return;
    const int beg = row_ptr[wid], end = row_ptr[wid + 1];
    const unsigned* tp = (const unsigned*)t;   // 64 uints per row
    float ax[8] = {0, 0, 0, 0, 0, 0, 0, 0};
    float ay[8] = {0, 0, 0, 0, 0, 0, 0, 0};
    int e = beg;
    for (; e + 7 < end; e += 8) {
        int sx[8];
        #pragma unroll
        for (int j = 0; j < 8; j++) sx[j] = esrc[e + j];
        unsigned v[8];
        #pragma unroll
        for (int j = 0; j < 8; j++) v[j] = tp[(size_t)sx[j] * 64 + lane];
        #pragma unroll
        for (int j = 0; j < 8; j++) {
            ax[j] += bf2f(v[j] & 0xffffu);
            ay[j] += bf2f(v[j] >> 16);
        }
    }
    for (; e + 3 < end; e += 4) {
        int sx[4];
        #pragma unroll
        for (int j = 0; j < 4; j++) sx[j] = esrc[e + j];
        unsigned v[4];
        #pragma unroll
        for (int j = 0; j < 4; j++) v[j] = tp[(size_t)sx[j] * 64 + lane];
        #pragma unroll
        for (int j = 0; j < 4; j++) {
            ax[j] += bf2f(v[j] & 0xffffu);
            ay[j] += bf2f(v[j] >> 16);
        }
    }
    for (; e < end; e++) {
        unsigned v = tp[(size_t)esrc[e] * 64 + lane];
        ax[0] += bf2f(v & 0xffffu); ay[0] += bf2f(v >> 16);
    }
    float sxx = ((ax[0] + ax[1]) + (ax[2] + ax[3])) + ((ax[4] + ax[5]) + (ax[6] + ax[7]));
    float syy = ((ay[0] + ay[1]) + (ay[2] + ay[3])) + ((ay[4] + ay[5]) + (ay[6] + ay[7]));
    float ni = norm_in[wid];
    float2 bb = ((const float2*)bias)[lane];
    float ox = fmaxf(sxx * ni + bb.x, 0.f);
    float oy = fmaxf(syy * ni + bb.y, 0.f);
    ((unsigned*)out)[(size_t)wid * 64 + lane] = f2bf(ox) | (f2bf(oy) << 16);
}

// 6b) 64-wide pull-aggregation, 8 gathers in flight, f32 out (feeds readout).
__global__ __launch_bounds__(256) void aggregate64_f32(
        const unsigned short* __restrict__ t, const int* __restrict__ row_ptr,
        const int* __restrict__ esrc, const float* __restrict__ norm_in,
        const float* __restrict__ bias, float* __restrict__ out, int n) {
    const int wid  = (blockIdx.x * blockDim.x + threadIdx.x) >> 6;
    const int lane = threadIdx.x & 63;
    if (wid >= n) return;
    const int beg = row_ptr[wid], end = row_ptr[wid + 1];
    float a[8] = {0, 0, 0, 0, 0, 0, 0, 0};
    int e = beg;
    for (; e + 7 < end; e += 8) {
        int sx[8];
        #pragma unroll
        for (int j = 0; j < 8; j++) sx[j] = esrc[e + j];
        unsigned short v[8];
        #pragma unroll
        for (int j = 0; j < 8; j++) v[j] = t[(size_t)sx[j] * 64 + lane];
        #pragma unroll
        for (int j = 0; j < 8; j++) a[j] += bf2f(v[j]);
    }
    for (; e + 3 < end; e += 4) {
        int sx[4];
        #pragma unroll
        for (int j = 0; j < 4; j++) sx[j] = esrc[e + j];
        unsigned short v[4];
        #pragma unroll
        for (int j = 0; j < 4; j++) v[j] = t[(size_t)sx[j] * 64 + lane];
        #pragma unroll
        for (int j = 0; j < 4; j++) a[j] += bf2f(v[j]);
    }
    for (; e < end; e++) a[0] += bf2f(t[(size_t)esrc[e] * 64 + lane]);
    float s = ((a[0] + a[1]) + (a[2] + a[3])) + ((a[4] + a[5]) + (a[6] + a[7]));
    float o = fmaxf(s * norm_in[wid] + bias[lane], 0.f);
    out[(size_t)wid * 64 + lane] = o;
}

// ---------------------------------------------------------------------------
// 7) per-graph sums exploiting sorted graph_ids
__global__ __launch_bounds__(256) void readout_partial(
        const float* __restrict__ h, const int* __restrict__ gids,
        float* __restrict__ sums, float* __restrict__ counts, int n) {
    const int wid  = (blockIdx.x * blockDim.x + threadIdx.x) >> 6;
    const int lane = threadIdx.x & 63;
    const int beg = wid * 64;
    if (beg >= n) return;
    const int end = min(beg + 64, n);
    int cur = gids[beg];
    float acc = 0.f; int cnt = 0;
    for (int i = beg; i < end; i++) {
        int g = gids[i];               // uniform across wave
        if (g != cur) {
            atomicAdd(&sums[(size_t)cur * 64 + lane], acc);
            if (lane == 0) atomicAdd(&counts[cur], (float)cnt);
            cur = g; acc = 0.f; cnt = 0;
        }
        acc += h[(size_t)i * 64 + lane];
        cnt++;
    }
    atomicAdd(&sums[(size_t)cur * 64 + lane], acc);
    if (lane == 0) atomicAdd(&counts[cur], (float)cnt);
}

__global__ void finalize_kernel(const float* __restrict__ sums, const float* __restrict__ counts,
                                float* __restrict__ out, int total) {
    int i = blockIdx.x * blockDim.x + threadIdx.x;
    if (i < total) out[i] = sums[i] / fmaxf(counts[i >> 6], 1.f);
}

// ---------------------------------------------------------------------------
extern "C" void kernel_launch(void* const* d_in, const int* in_sizes, int n_in,
                              void* d_out, int out_size, void* d_ws, size_t ws_size,
                              hipStream_t stream) {
    const float* n_feat = (const float*)d_in[0];
    const float* W0 = (const float*)d_in[1];
    const float* b0 = (const float*)d_in[2];
    const float* W1 = (const float*)d_in[3];
    const float* b1 = (const float*)d_in[4];
    const float* W2 = (const float*)d_in[5];
    const float* b2 = (const float*)d_in[6];
    const int* src  = (const int*)d_in[7];
    const int* dst  = (const int*)d_in[8];
    const int* gids = (const int*)d_in[9];
    float* out = (float*)d_out;

    char* ws = (char*)d_ws;
    // layout (bytes):
    int*            esrc       = (int*)   (ws + 0);         // E ints (3.2 MB)
    float*          norm_out   = (float*) (ws + 3200000);   // NN floats
    float*          norm_in    = (float*) (ws + 3400000);   // NN floats
    int*            deg_in_tot = (int*)   (ws + 3600000);   // NN ints
    int*            row_ptr    = (int*)   (ws + 3800000);   // NN+1 ints
    int*            bsum       = (int*)   (ws + 4000064);   // SCB ints
    float*          sums       = (float*) (ws + 4200064);   // 500*64 floats
    float*          counts     = (float*) (ws + 4328064);   // 500 floats
    unsigned short* bufA       = (unsigned short*)(ws + 4330112);  // NN*128 bf16 (12.8 MB)
    // degree partials overlay bufA (dead before first gemm writes bufA)
    int*            pin        = (int*)   (ws + 4330112);           // NC*NN ints
    int*            pout       = (int*)   (ws + 4330112 + 6400000); // NC*NN ints
    int*            pcur       = (int*)   (ws + 17200000);  // NC*NN ints (6.4 MB)
    unsigned short* bufB16     = (unsigned short*)(ws + 29930112);  // NN*128 bf16 (h1/h2)
    float*          bufBf      = (float*) (ws + 29930112);  // NN*64 f32 (h3)

    // graph structure (device-side, every call) — zero global atomics in hot path
    degree_lds_kernel<<<NR * NC, 256, 0, stream>>>(src, dst, pin, pout, bsum);
    reduce_norms_kernel<<<(NN + 255) / 256, 256, 0, stream>>>(pin, pout, deg_in_tot,
                                                              norm_in, norm_out, bsum,
                                                              sums, NN);
    scan_apply<<<SCB, 1024, 0, stream>>>(deg_in_tot, bsum, row_ptr, NN);
    chunk_offsets_kernel<<<(NN + 255) / 256, 256, 0, stream>>>(pin, row_ptr, pcur, NN);
    place_lds_kernel<<<NR * NC, 256, 0, stream>>>(src, dst, pcur, esrc);

    const int g128 = (NN + 127) / 128;   // gemm <128,128>
    const int g64  = (NN + 255) / 256;   // gemm <64,256>
    const int agg_grid = (NN + 3) / 4;   // 4 waves/block, 1 wave/node

    // layer 1: t0 = bf16((n_feat*norm_out)@W0) ; h1 = bf16(relu(norm_in*agg(t0)+b0))
    gemm_reg_bf<128, 128, false><<<g128, 256, 0, stream>>>(n_feat, W0, norm_out, bufA, NN);
    aggregate128_h16<<<agg_grid, 256, 0, stream>>>(bufA, row_ptr, esrc, norm_in, b0, bufB16, NN);
    // layer 2 (bf16 A)
    gemm_reg_bf<128, 128, true><<<g128, 256, 0, stream>>>(bufB16, W1, norm_out, bufA, NN);
    aggregate128_h16<<<agg_grid, 256, 0, stream>>>(bufA, row_ptr, esrc, norm_in, b1, bufB16, NN);
    // layer 3 (bf16 A, 64-wide out)
    gemm_reg_bf<64, 256, true><<<g64, 256, 0, stream>>>(bufB16, W2, norm_out, bufA, NN);
    aggregate64_f32<<<agg_grid, 256, 0, stream>>>(bufA, row_ptr, esrc, norm_in, b2, bufBf, NN);

    // readout: per-graph mean (graph_ids sorted)
    const int ro_threads = ((NN + 63) / 64) * 64;
    readout_partial<<<(ro_threads + 255) / 256, 256, 0, stream>>>(bufBf, gids, sums, counts, NN);
    finalize_kernel<<<(NG * 64 + 255) / 256, 256, 0, stream>>>(sums, counts, out, NG * 64);
}

// Round 14
// 353.258 us; speedup vs baseline: 1.1950x; 1.0163x over previous
//
#include <hip/hip_runtime.h>
#include <hip/hip_bf16.h>

// Problem constants (match reference)
#define NN 50000
#define NE 800000
#define NG 500
// D_IN = D_HID = 128, D_OUT = 64

// degree/placement decomposition
#define NR 8            // node ranges (LDS histogram = 2 x NN/NR ints = 50 KB)
#define NC 32           // edge chunks
#define RNG (NN / NR)   // 6250 nodes per range
#define CHE (NE / NC)   // 25000 edges per chunk
#define SCB 13          // scan blocks: ceil(NN / 4096)

// bf16 helpers (RNE pack, shift-unpack)
__device__ __forceinline__ unsigned f2bf(float f) {
    unsigned u = __float_as_uint(f);
    return (u + 0x7fffu + ((u >> 16) & 1u)) >> 16;
}
__device__ __forceinline__ float bf2f(unsigned u16) {
    return __uint_as_float(u16 << 16);
}

// ---------------------------------------------------------------------------
// 1) degree count with ZERO global atomics: LDS histograms + non-atomic flush.
//    Also zeroes bsum (13 ints) for the downstream scan.
__global__ __launch_bounds__(256) void degree_lds_kernel(
        const int* __restrict__ src, const int* __restrict__ dst,
        int* __restrict__ pin, int* __restrict__ pout, int* __restrict__ bsum) {
    __shared__ int hin[RNG], hout[RNG];
    const int tid   = threadIdx.x;
    const int r     = blockIdx.x & (NR - 1);
    const int c     = blockIdx.x / NR;
    const int rbase = r * RNG;
    if (blockIdx.x == 0 && tid < SCB) bsum[tid] = 0;
    for (int i = tid; i < RNG; i += 256) { hin[i] = 0; hout[i] = 0; }
    __syncthreads();
    const int4* s4 = (const int4*)(src + c * CHE);
    const int4* d4 = (const int4*)(dst + c * CHE);
    for (int i = tid; i < CHE / 4; i += 256) {
        int4 s = s4[i];
        int4 d = d4[i];
        unsigned a;
        a = (unsigned)(d.x - rbase); if (a < RNG) atomicAdd(&hin[a], 1);
        a = (unsigned)(d.y - rbase); if (a < RNG) atomicAdd(&hin[a], 1);
        a = (unsigned)(d.z - rbase); if (a < RNG) atomicAdd(&hin[a], 1);
        a = (unsigned)(d.w - rbase); if (a < RNG) atomicAdd(&hin[a], 1);
        a = (unsigned)(s.x - rbase); if (a < RNG) atomicAdd(&hout[a], 1);
        a = (unsigned)(s.y - rbase); if (a < RNG) atomicAdd(&hout[a], 1);
        a = (unsigned)(s.z - rbase); if (a < RNG) atomicAdd(&hout[a], 1);
        a = (unsigned)(s.w - rbase); if (a < RNG) atomicAdd(&hout[a], 1);
    }
    __syncthreads();
    for (int i = tid; i < RNG; i += 256) {
        pin [c * NN + rbase + i] = hin[i];
        pout[c * NN + rbase + i] = hout[i];
    }
}

// ---------------------------------------------------------------------------
// 2) reduce partials -> deg_in_tot + norms + per-4096-chunk sums + zero sums.
__global__ __launch_bounds__(256) void reduce_norms_kernel(
        const int* __restrict__ pin, const int* __restrict__ pout,
        int* __restrict__ deg_in_tot, float* __restrict__ norm_in,
        float* __restrict__ norm_out, int* __restrict__ bsum,
        float* __restrict__ sums, int n) {
    const int tid = threadIdx.x, lane = tid & 63, wv = tid >> 6;
    const int i = blockIdx.x * 256 + tid;
    if (i < NG * 64 + NG) sums[i] = 0.f;   // zero sums+counts (contiguous)
    int di = 0, dq = 0;
    if (i < n) {
        #pragma unroll
        for (int c = 0; c < NC; c++) {
            di += pin [c * NN + i];
            dq += pout[c * NN + i];
        }
        deg_in_tot[i] = di;
        norm_in[i]  = di > 0 ? 1.0f / sqrtf((float)di) : 0.f;
        norm_out[i] = dq > 0 ? 1.0f / sqrtf((float)dq) : 0.f;
    }
    __shared__ int wsum[4];
    int s = di;
    #pragma unroll
    for (int off = 32; off > 0; off >>= 1) s += __shfl_down(s, off);
    if (lane == 0) wsum[wv] = s;
    __syncthreads();
    if (tid == 0) {
        int t = wsum[0] + wsum[1] + wsum[2] + wsum[3];
        atomicAdd(&bsum[blockIdx.x >> 4], t);
    }
}

// ---------------------------------------------------------------------------
// 3) per-chunk local scan + global base -> row_ptr (tiny traffic, 13 blocks)
__global__ __launch_bounds__(1024) void scan_apply(
        const int* __restrict__ deg, const int* __restrict__ bsum,
        int* __restrict__ row_ptr, int n) {
    __shared__ int wsum[16];
    const int tid = threadIdx.x, lane = tid & 63, wv = tid >> 6;
    const int b = blockIdx.x;
    int base = 0;
    for (int j = 0; j < SCB; j++) base += (j < b) ? bsum[j] : 0;
    const int i0 = b * 4096 + tid * 4;
    int v0 = 0, v1 = 0, v2 = 0, v3 = 0;
    if (i0 + 3 < n) {
        int4 v = *(const int4*)(deg + i0);
        v0 = v.x; v1 = v.y; v2 = v.z; v3 = v.w;
    } else if (i0 < n) {
        v0 = deg[i0];
        if (i0 + 1 < n) v1 = deg[i0 + 1];
        if (i0 + 2 < n) v2 = deg[i0 + 2];
    }
    const int l0 = v0, l1 = l0 + v1, l2 = l1 + v2, l3 = l2 + v3;
    int x = l3;
    #pragma unroll
    for (int off = 1; off < 64; off <<= 1) {
        int y = __shfl_up(x, off);
        if (lane >= off) x += y;
    }
    if (lane == 63) wsum[wv] = x;
    __syncthreads();
    if (wv == 0) {
        int t = (lane < 16) ? wsum[lane] : 0;
        int s = t;
        #pragma unroll
        for (int off = 1; off < 16; off <<= 1) {
            int y = __shfl_up(s, off);
            if (lane >= off) s += y;
        }
        if (lane < 16) wsum[lane] = s - t;   // exclusive wave offsets
    }
    __syncthreads();
    const int pre = base + wsum[wv] + (x - l3);  // global exclusive prefix at i0
    if (b == 0 && tid == 0) row_ptr[0] = 0;
    if (i0 < n)     row_ptr[i0 + 1] = pre + l0;
    if (i0 + 1 < n) row_ptr[i0 + 2] = pre + l1;
    if (i0 + 2 < n) row_ptr[i0 + 3] = pre + l2;
    if (i0 + 3 < n) row_ptr[i0 + 4] = pre + l3;
}

// 3c) per-(node,chunk) placement offsets at full parallelism (196 blocks)
__global__ void chunk_offsets_kernel(const int* __restrict__ pin,
                                     const int* __restrict__ row_ptr,
                                     int* __restrict__ pcur, int n) {
    int i = blockIdx.x * blockDim.x + threadIdx.x;
    if (i >= n) return;
    int off = row_ptr[i];
    #pragma unroll
    for (int c = 0; c < NC; c++) {
        pcur[c * NN + i] = off;
        off += pin[c * NN + i];
    }
}

// ---------------------------------------------------------------------------
// 4) CSR placement with ZERO global atomics: LDS cursors per (range,chunk).
__global__ __launch_bounds__(256) void place_lds_kernel(
        const int* __restrict__ src, const int* __restrict__ dst,
        const int* __restrict__ pcur, int* __restrict__ esrc) {
    __shared__ int lcur[RNG];
    const int tid   = threadIdx.x;
    const int r     = blockIdx.x & (NR - 1);
    const int c     = blockIdx.x / NR;
    const int rbase = r * RNG;
    for (int i = tid; i < RNG; i += 256) lcur[i] = pcur[c * NN + rbase + i];
    __syncthreads();
    const int4* s4 = (const int4*)(src + c * CHE);
    const int4* d4 = (const int4*)(dst + c * CHE);
    for (int i = tid; i < CHE / 4; i += 256) {
        int4 s = s4[i];
        int4 d = d4[i];
        unsigned a;
        a = (unsigned)(d.x - rbase); if (a < RNG) esrc[atomicAdd(&lcur[a], 1)] = s.x;
        a = (unsigned)(d.y - rbase); if (a < RNG) esrc[atomicAdd(&lcur[a], 1)] = s.y;
        a = (unsigned)(d.z - rbase); if (a < RNG) esrc[atomicAdd(&lcur[a], 1)] = s.z;
        a = (unsigned)(d.w - rbase); if (a < RNG) esrc[atomicAdd(&lcur[a], 1)] = s.w;
    }
}

// ---------------------------------------------------------------------------
// 5) GEMM: out = bf16((A*norm) @ W).  RETILED: ROWS=64 (782 blocks = 3/CU vs
//    old 1.5/CU), thread tile 4 x TC (TC=DO/16), At pad +1 (stride 65 = 1 bank
//    -> staging writes ~2-way, was 4-way at stride 132).
template<int DO, bool A16>
__global__ __launch_bounds__(256) void gemm_reg_bf(
        const void* __restrict__ Av, const float* __restrict__ W,
        const float* __restrict__ norm, unsigned short* __restrict__ out, int nrows) {
    constexpr int DI   = 128;
    constexpr int KC   = 32;          // K-chunk
    constexpr int TC   = DO / 16;     // cols per thread (8 for DO=128, 4 for DO=64)
    constexpr int CXN  = 16;          // col-threads
    constexpr int RYN  = 16;          // row-threads
    constexpr int ROWS = RYN * 4;     // 64 rows per block
    __shared__ float At[KC][ROWS + 1];   // +1 pad: bank stride 1
    __shared__ float Wl[KC][DO + 4];

    const int tid  = threadIdx.x;
    const int cx   = tid % CXN;
    const int ry   = tid / CXN;
    const int row0 = blockIdx.x * ROWS;

    float acc[4][TC] = {};

    for (int kc = 0; kc < DI; kc += KC) {
        __syncthreads();
        constexpr int AF4 = ROWS * KC / 4;   // 512 -> 2 iters
        #pragma unroll
        for (int i = tid; i < AF4; i += 256) {
            int r  = i >> 3;
            int kq = i & 7;
            int gr = row0 + r;
            float v0 = 0.f, v1 = 0.f, v2 = 0.f, v3 = 0.f;
            if (gr < nrows) {
                float s = norm[gr];
                if constexpr (A16) {
                    const unsigned short* A = (const unsigned short*)Av;
                    uint2 u = *(const uint2*)(A + (size_t)gr * DI + kc + kq * 4);
                    v0 = bf2f(u.x & 0xffffu) * s; v1 = bf2f(u.x >> 16) * s;
                    v2 = bf2f(u.y & 0xffffu) * s; v3 = bf2f(u.y >> 16) * s;
                } else {
                    const float* A = (const float*)Av;
                    float4 v = ((const float4*)(A + (size_t)gr * DI + kc))[kq];
                    v0 = v.x * s; v1 = v.y * s; v2 = v.z * s; v3 = v.w * s;
                }
            }
            At[kq * 4 + 0][r] = v0;
            At[kq * 4 + 1][r] = v1;
            At[kq * 4 + 2][r] = v2;
            At[kq * 4 + 3][r] = v3;
        }
        constexpr int WF4 = KC * DO / 4;
        #pragma unroll
        for (int i = tid; i < WF4; i += 256) {
            int k  = i / (DO / 4);
            int c4 = i % (DO / 4);
            *(float4*)&Wl[k][c4 * 4] = ((const float4*)(W + (size_t)(kc + k) * DO))[c4];
        }
        __syncthreads();
        #pragma unroll 8
        for (int k = 0; k < KC; k++) {
            float4 av = *(const float4*)&At[k][ry * 4];
            float a[4] = {av.x, av.y, av.z, av.w};
            float w[TC];
            *(float4*)&w[0] = *(const float4*)&Wl[k][cx * 4];
            if constexpr (TC == 8)
                *(float4*)&w[4] = *(const float4*)&Wl[k][DO / 2 + cx * 4];
            #pragma unroll
            for (int i = 0; i < 4; i++)
                #pragma unroll
                for (int j = 0; j < TC; j++)
                    acc[i][j] += a[i] * w[j];
        }
    }
    #pragma unroll
    for (int i = 0; i < 4; i++) {
        int gr = row0 + ry * 4 + i;
        if (gr < nrows) {
            unsigned short* orow = out + (size_t)gr * DO;
            uint2 lo;
            lo.x = f2bf(acc[i][0]) | (f2bf(acc[i][1]) << 16);
            lo.y = f2bf(acc[i][2]) | (f2bf(acc[i][3]) << 16);
            ((uint2*)orow)[cx] = lo;                       // cols cx*4..+3
            if constexpr (TC == 8) {
                uint2 hi;
                hi.x = f2bf(acc[i][4]) | (f2bf(acc[i][5]) << 16);
                hi.y = f2bf(acc[i][6]) | (f2bf(acc[i][7]) << 16);
                ((uint2*)(orow + DO / 2))[cx] = hi;        // cols DO/2+cx*4..+3
            }
        }
    }
}

// ---------------------------------------------------------------------------
// 6a) 128-wide pull-aggregation, 8 gathers in flight (latency hiding).
__global__ __launch_bounds__(256) void aggregate128_h16(
        const unsigned short* __restrict__ t, const int* __restrict__ row_ptr,
        const int* __restrict__ esrc, const float* __restrict__ norm_in,
        const float* __restrict__ bias, unsigned short* __restrict__ out, int n) {
    const int wid  = (blockIdx.x * blockDim.x + threadIdx.x) >> 6;
    const int lane = threadIdx.x & 63;
    if (wid >= n) return;
    const int beg = row_ptr[wid], end = row_ptr[wid + 1];
    const unsigned* tp = (const unsigned*)t;   // 64 uints per row
    float ax[8] = {0, 0, 0, 0, 0, 0, 0, 0};
    float ay[8] = {0, 0, 0, 0, 0, 0, 0, 0};
    int e = beg;
    for (; e + 7 < end; e += 8) {
        int sx[8];
        #pragma unroll
        for (int j = 0; j < 8; j++) sx[j] = esrc[e + j];
        unsigned v[8];
        #pragma unroll
        for (int j = 0; j < 8; j++) v[j] = tp[(size_t)sx[j] * 64 + lane];
        #pragma unroll
        for (int j = 0; j < 8; j++) {
            ax[j] += bf2f(v[j] & 0xffffu);
            ay[j] += bf2f(v[j] >> 16);
        }
    }
    for (; e + 3 < end; e += 4) {
        int sx[4];
        #pragma unroll
        for (int j = 0; j < 4; j++) sx[j] = esrc[e + j];
        unsigned v[4];
        #pragma unroll
        for (int j = 0; j < 4; j++) v[j] = tp[(size_t)sx[j] * 64 + lane];
        #pragma unroll
        for (int j = 0; j < 4; j++) {
            ax[j] += bf2f(v[j] & 0xffffu);
            ay[j] += bf2f(v[j] >> 16);
        }
    }
    for (; e < end; e++) {
        unsigned v = tp[(size_t)esrc[e] * 64 + lane];
        ax[0] += bf2f(v & 0xffffu); ay[0] += bf2f(v >> 16);
    }
    float sxx = ((ax[0] + ax[1]) + (ax[2] + ax[3])) + ((ax[4] + ax[5]) + (ax[6] + ax[7]));
    float syy = ((ay[0] + ay[1]) + (ay[2] + ay[3])) + ((ay[4] + ay[5]) + (ay[6] + ay[7]));
    float ni = norm_in[wid];
    float2 bb = ((const float2*)bias)[lane];
    float ox = fmaxf(sxx * ni + bb.x, 0.f);
    float oy = fmaxf(syy * ni + bb.y, 0.f);
    ((unsigned*)out)[(size_t)wid * 64 + lane] = f2bf(ox) | (f2bf(oy) << 16);
}

// 6b) 64-wide pull-aggregation, 8 gathers in flight, f32 out (feeds readout).
__global__ __launch_bounds__(256) void aggregate64_f32(
        const unsigned short* __restrict__ t, const int* __restrict__ row_ptr,
        const int* __restrict__ esrc, const float* __restrict__ norm_in,
        const float* __restrict__ bias, float* __restrict__ out, int n) {
    const int wid  = (blockIdx.x * blockDim.x + threadIdx.x) >> 6;
    const int lane = threadIdx.x & 63;
    if (wid >= n) return;
    const int beg = row_ptr[wid], end = row_ptr[wid + 1];
    float a[8] = {0, 0, 0, 0, 0, 0, 0, 0};
    int e = beg;
    for (; e + 7 < end; e += 8) {
        int sx[8];
        #pragma unroll
        for (int j = 0; j < 8; j++) sx[j] = esrc[e + j];
        unsigned short v[8];
        #pragma unroll
        for (int j = 0; j < 8; j++) v[j] = t[(size_t)sx[j] * 64 + lane];
        #pragma unroll
        for (int j = 0; j < 8; j++) a[j] += bf2f(v[j]);
    }
    for (; e + 3 < end; e += 4) {
        int sx[4];
        #pragma unroll
        for (int j = 0; j < 4; j++) sx[j] = esrc[e + j];
        unsigned short v[4];
        #pragma unroll
        for (int j = 0; j < 4; j++) v[j] = t[(size_t)sx[j] * 64 + lane];
        #pragma unroll
        for (int j = 0; j < 4; j++) a[j] += bf2f(v[j]);
    }
    for (; e < end; e++) a[0] += bf2f(t[(size_t)esrc[e] * 64 + lane]);
    float s = ((a[0] + a[1]) + (a[2] + a[3])) + ((a[4] + a[5]) + (a[6] + a[7]));
    float o = fmaxf(s * norm_in[wid] + bias[lane], 0.f);
    out[(size_t)wid * 64 + lane] = o;
}

// ---------------------------------------------------------------------------
// 7) per-graph sums exploiting sorted graph_ids
__global__ __launch_bounds__(256) void readout_partial(
        const float* __restrict__ h, const int* __restrict__ gids,
        float* __restrict__ sums, float* __restrict__ counts, int n) {
    const int wid  = (blockIdx.x * blockDim.x + threadIdx.x) >> 6;
    const int lane = threadIdx.x & 63;
    const int beg = wid * 64;
    if (beg >= n) return;
    const int end = min(beg + 64, n);
    int cur = gids[beg];
    float acc = 0.f; int cnt = 0;
    for (int i = beg; i < end; i++) {
        int g = gids[i];               // uniform across wave
        if (g != cur) {
            atomicAdd(&sums[(size_t)cur * 64 + lane], acc);
            if (lane == 0) atomicAdd(&counts[cur], (float)cnt);
            cur = g; acc = 0.f; cnt = 0;
        }
        acc += h[(size_t)i * 64 + lane];
        cnt++;
    }
    atomicAdd(&sums[(size_t)cur * 64 + lane], acc);
    if (lane == 0) atomicAdd(&counts[cur], (float)cnt);
}

__global__ void finalize_kernel(const float* __restrict__ sums, const float* __restrict__ counts,
                                float* __restrict__ out, int total) {
    int i = blockIdx.x * blockDim.x + threadIdx.x;
    if (i < total) out[i] = sums[i] / fmaxf(counts[i >> 6], 1.f);
}

// ---------------------------------------------------------------------------
extern "C" void kernel_launch(void* const* d_in, const int* in_sizes, int n_in,
                              void* d_out, int out_size, void* d_ws, size_t ws_size,
                              hipStream_t stream) {
    const float* n_feat = (const float*)d_in[0];
    const float* W0 = (const float*)d_in[1];
    const float* b0 = (const float*)d_in[2];
    const float* W1 = (const float*)d_in[3];
    const float* b1 = (const float*)d_in[4];
    const float* W2 = (const float*)d_in[5];
    const float* b2 = (const float*)d_in[6];
    const int* src  = (const int*)d_in[7];
    const int* dst  = (const int*)d_in[8];
    const int* gids = (const int*)d_in[9];
    float* out = (float*)d_out;

    char* ws = (char*)d_ws;
    // layout (bytes):
    int*            esrc       = (int*)   (ws + 0);         // E ints (3.2 MB)
    float*          norm_out   = (float*) (ws + 3200000);   // NN floats
    float*          norm_in    = (float*) (ws + 3400000);   // NN floats
    int*            deg_in_tot = (int*)   (ws + 3600000);   // NN ints
    int*            row_ptr    = (int*)   (ws + 3800000);   // NN+1 ints
    int*            bsum       = (int*)   (ws + 4000064);   // SCB ints
    float*          sums       = (float*) (ws + 4200064);   // 500*64 floats
    float*          counts     = (float*) (ws + 4328064);   // 500 floats
    unsigned short* bufA       = (unsigned short*)(ws + 4330112);  // NN*128 bf16 (12.8 MB)
    // degree partials overlay bufA (dead before first gemm writes bufA)
    int*            pin        = (int*)   (ws + 4330112);           // NC*NN ints
    int*            pout       = (int*)   (ws + 4330112 + 6400000); // NC*NN ints
    int*            pcur       = (int*)   (ws + 17200000);  // NC*NN ints (6.4 MB)
    unsigned short* bufB16     = (unsigned short*)(ws + 29930112);  // NN*128 bf16 (h1/h2)
    float*          bufBf      = (float*) (ws + 29930112);  // NN*64 f32 (h3)

    // graph structure (device-side, every call) — zero global atomics in hot path
    degree_lds_kernel<<<NR * NC, 256, 0, stream>>>(src, dst, pin, pout, bsum);
    reduce_norms_kernel<<<(NN + 255) / 256, 256, 0, stream>>>(pin, pout, deg_in_tot,
                                                              norm_in, norm_out, bsum,
                                                              sums, NN);
    scan_apply<<<SCB, 1024, 0, stream>>>(deg_in_tot, bsum, row_ptr, NN);
    chunk_offsets_kernel<<<(NN + 255) / 256, 256, 0, stream>>>(pin, row_ptr, pcur, NN);
    place_lds_kernel<<<NR * NC, 256, 0, stream>>>(src, dst, pcur, esrc);

    const int ggrid    = (NN + 63) / 64;   // 782 blocks, all gemm layers
    const int agg_grid = (NN + 3) / 4;     // 4 waves/block, 1 wave/node

    // layer 1: t0 = bf16((n_feat*norm_out)@W0) ; h1 = bf16(relu(norm_in*agg(t0)+b0))
    gemm_reg_bf<128, false><<<ggrid, 256, 0, stream>>>(n_feat, W0, norm_out, bufA, NN);
    aggregate128_h16<<<agg_grid, 256, 0, stream>>>(bufA, row_ptr, esrc, norm_in, b0, bufB16, NN);
    // layer 2 (bf16 A)
    gemm_reg_bf<128, true><<<ggrid, 256, 0, stream>>>(bufB16, W1, norm_out, bufA, NN);
    aggregate128_h16<<<agg_grid, 256, 0, stream>>>(bufA, row_ptr, esrc, norm_in, b1, bufB16, NN);
    // layer 3 (bf16 A, 64-wide out)
    gemm_reg_bf<64, true><<<ggrid, 256, 0, stream>>>(bufB16, W2, norm_out, bufA, NN);
    aggregate64_f32<<<agg_grid, 256, 0, stream>>>(bufA, row_ptr, esrc, norm_in, b2, bufBf, NN);

    // readout: per-graph mean (graph_ids sorted)
    const int ro_threads = ((NN + 63) / 64) * 64;
    readout_partial<<<(ro_threads + 255) / 256, 256, 0, stream>>>(bufBf, gids, sums, counts, NN);
    finalize_kernel<<<(NG * 64 + 255) / 256, 256, 0, stream>>>(sums, counts, out, NG * 64);
}